// Round 3
// baseline (188.737 us; speedup 1.0000x reference)
//
#include <hip/hip_runtime.h>

// Problem constants (match reference)
#define BB 32
#define KK 128
#define SS 48
#define LL 2
#define HH 128
#define AA 500

static constexpr float NEG_INF = -1e30f;

// Output layout (flat float32, concatenated in reference return order)
static constexpr long SZ_BK    = (long)BB * KK;                 // 4096
static constexpr long SZ_HID   = (long)BB * KK * SS * LL * HH;  // 50331648
static constexpr long SZ_TREE  = (long)BB * KK * SS * HH;       // 25165824
static constexpr long SZ_ACT   = (long)BB * KK * AA;            // 2048000

static constexpr long OFF_GEN   = 0;
static constexpr long OFF_DISC  = OFF_GEN  + SZ_BK;
static constexpr long OFF_HID   = OFF_DISC + SZ_BK;
static constexpr long OFF_CELL  = OFF_HID  + SZ_HID;
static constexpr long OFF_TREE  = OFF_CELL + SZ_HID;
static constexpr long OFF_WID   = OFF_TREE + SZ_TREE;
static constexpr long OFF_NCONS = OFF_WID  + BB;
static constexpr long OFF_NOPEN = OFF_NCONS + SZ_BK;
static constexpr long OFF_ACT   = OFF_NOPEN + SZ_BK;
static constexpr long OFF_APOS  = OFF_ACT  + SZ_ACT;
static constexpr long OFF_PTR   = OFF_APOS + SZ_BK;
// total = OFF_PTR + SZ_BK = 127901728 floats

typedef float f32x4 __attribute__((ext_vector_type(4)));
typedef int   i32x4 __attribute__((ext_vector_type(4)));

// Single fused kernel: one block per destination row (b,k).
// Prologue: recompute the stable descending rank of the masked gen_ll row
// (K=128, LDS broadcast loop ~400 cycles, overlapped across the 8 resident
// blocks/CU with other blocks' streaming). The thread whose rank == k writes
// the 6 small sorted outputs for this row and publishes src to LDS.
// Body: nontemporal float4 stream of hiddens/cells/trees/actions row
// src -> k (every byte touched exactly once; keep it out of L2).
__global__ __launch_bounds__(256) void shrink_fused(
    const float* __restrict__ gen_ll,
    const float* __restrict__ disc_ll,
    const f32x4* __restrict__ hiddens,
    const f32x4* __restrict__ cells,
    const f32x4* __restrict__ trees,
    const i32x4* __restrict__ actions,
    const int*   __restrict__ beam_widths,
    const int*   __restrict__ ncons,
    const int*   __restrict__ nopen,
    const int*   __restrict__ actions_pos,
    const int*   __restrict__ pointer,
    const int*   __restrict__ size_ptr,
    float*       __restrict__ out)
{
    const int bk  = blockIdx.x;        // 0..4095
    const int b   = bk >> 7;
    const int k   = bk & (KK - 1);
    const int tid = threadIdx.x;       // 0..255

    __shared__ float mv[KK];
    __shared__ int   s_src;

    const int bw = beam_widths[b];
    if (tid < KK) {
        float v = gen_ll[b * KK + tid];
        if (tid >= bw) v = NEG_INF;
        mv[tid] = v;
    }
    __syncthreads();

    if (tid < KK) {
        const float v = mv[tid];
        int rank = 0;
#pragma unroll 8
        for (int j = 0; j < KK; ++j) {
            float vj = mv[j];  // LDS broadcast (same addr all lanes) - free
            rank += (vj > v) || (vj == v && j < tid);
        }
        if (rank == k) {
            s_src = tid;
            // small sorted outputs for this destination row
            out[OFF_GEN   + bk] = v;
            out[OFF_DISC  + bk] = disc_ll[b * KK + tid];
            out[OFF_NCONS + bk] = (float)ncons[b * KK + tid];
            out[OFF_NOPEN + bk] = (float)nopen[b * KK + tid];
            out[OFF_APOS  + bk] = (float)actions_pos[b * KK + tid];
            out[OFF_PTR   + bk] = (float)pointer[b * KK + tid];
        }
        if (tid == 0 && k == 0) {
            int sz = size_ptr[0];
            out[OFF_WID + b] = (float)(bw < sz ? bw : sz);
        }
    }
    __syncthreads();

    const long srow = (long)b * KK + s_src;
    const long drow = bk;

    // hiddens: 3072 float4 per row, 12 iters of 256 lanes
    {
        const f32x4* in = hiddens + srow * 3072;
        f32x4*       o  = (f32x4*)(out + OFF_HID) + drow * 3072;
#pragma unroll
        for (int it = 0; it < 12; ++it) {
            const int r = it * 256 + tid;
            __builtin_nontemporal_store(__builtin_nontemporal_load(&in[r]), &o[r]);
        }
    }
    // cells: same shape
    {
        const f32x4* in = cells + srow * 3072;
        f32x4*       o  = (f32x4*)(out + OFF_CELL) + drow * 3072;
#pragma unroll
        for (int it = 0; it < 12; ++it) {
            const int r = it * 256 + tid;
            __builtin_nontemporal_store(__builtin_nontemporal_load(&in[r]), &o[r]);
        }
    }
    // trees: 1536 float4 per row, 6 iters
    {
        const f32x4* in = trees + srow * 1536;
        f32x4*       o  = (f32x4*)(out + OFF_TREE) + drow * 1536;
#pragma unroll
        for (int it = 0; it < 6; ++it) {
            const int r = it * 256 + tid;
            __builtin_nontemporal_store(__builtin_nontemporal_load(&in[r]), &o[r]);
        }
    }
    // actions: 125 int4 per row -> float4
    if (tid < 125) {
        i32x4 a = __builtin_nontemporal_load(&actions[srow * 125 + tid]);
        f32x4 v;
        v.x = (float)a.x; v.y = (float)a.y; v.z = (float)a.z; v.w = (float)a.w;
        __builtin_nontemporal_store(v, &((f32x4*)(out + OFF_ACT))[drow * 125 + tid]);
    }
}

extern "C" void kernel_launch(void* const* d_in, const int* in_sizes, int n_in,
                              void* d_out, int out_size, void* d_ws, size_t ws_size,
                              hipStream_t stream) {
    const float* gen_ll      = (const float*)d_in[0];
    const float* disc_ll     = (const float*)d_in[1];
    const float* hiddens     = (const float*)d_in[2];
    const float* cells       = (const float*)d_in[3];
    const float* trees       = (const float*)d_in[4];
    const int*   beam_widths = (const int*)d_in[5];
    const int*   ncons       = (const int*)d_in[6];
    const int*   nopen       = (const int*)d_in[7];
    const int*   actions     = (const int*)d_in[8];
    const int*   actions_pos = (const int*)d_in[9];
    const int*   pointer     = (const int*)d_in[10];
    const int*   size_ptr    = (const int*)d_in[11];

    float* out = (float*)d_out;

    shrink_fused<<<BB * KK, 256, 0, stream>>>(
        gen_ll, disc_ll,
        (const f32x4*)hiddens, (const f32x4*)cells, (const f32x4*)trees,
        (const i32x4*)actions,
        beam_widths, ncons, nopen, actions_pos, pointer, size_ptr,
        out);
}

// Round 4
// 172.796 us; speedup vs baseline: 1.0923x; 1.0923x over previous
//
#include <hip/hip_runtime.h>

// Problem constants (match reference)
#define BB 32
#define KK 128
#define SS 48
#define LL 2
#define HH 128
#define AA 500

static constexpr float NEG_INF = -1e30f;

// Output layout (flat float32, concatenated in return order)
static constexpr long SZ_BK    = (long)BB * KK;                 // 4096
static constexpr long SZ_HID   = (long)BB * KK * SS * LL * HH;  // 50331648
static constexpr long SZ_TREE  = (long)BB * KK * SS * HH;       // 25165824
static constexpr long SZ_ACT   = (long)BB * KK * AA;            // 2048000

static constexpr long OFF_GEN   = 0;
static constexpr long OFF_DISC  = OFF_GEN  + SZ_BK;
static constexpr long OFF_HID   = OFF_DISC + SZ_BK;
static constexpr long OFF_CELL  = OFF_HID  + SZ_HID;
static constexpr long OFF_TREE  = OFF_CELL + SZ_HID;
static constexpr long OFF_WID   = OFF_TREE + SZ_TREE;
static constexpr long OFF_NCONS = OFF_WID  + BB;
static constexpr long OFF_NOPEN = OFF_NCONS + SZ_BK;
static constexpr long OFF_ACT   = OFF_NOPEN + SZ_BK;
static constexpr long OFF_APOS  = OFF_ACT  + SZ_ACT;
static constexpr long OFF_PTR   = OFF_APOS + SZ_BK;
// total = OFF_PTR + SZ_BK = 127901728 floats

typedef float f32x4 __attribute__((ext_vector_type(4)));
typedef int   i32x4 __attribute__((ext_vector_type(4)));

// One block per batch row: stable descending sort of masked gen_ll (K=128),
// write permutation + all small sorted outputs.
__global__ void sort_small_kernel(
    const float* __restrict__ gen_ll,
    const float* __restrict__ disc_ll,
    const int*   __restrict__ beam_widths,
    const int*   __restrict__ ncons,
    const int*   __restrict__ nopen,
    const int*   __restrict__ actions_pos,
    const int*   __restrict__ pointer,
    const int*   __restrict__ size_ptr,
    float*       __restrict__ out,
    int*         __restrict__ perm_ws)
{
    const int b = blockIdx.x;
    const int i = threadIdx.x;  // 0..127

    __shared__ float mv[KK];
    __shared__ int   perm[KK];

    const int bw = beam_widths[b];
    float v = gen_ll[b * KK + i];
    if (i >= bw) v = NEG_INF;
    mv[i] = v;
    __syncthreads();

    // stable descending rank: strictly greater, or equal with lower index
    int rank = 0;
#pragma unroll 8
    for (int j = 0; j < KK; ++j) {
        float vj = mv[j];
        rank += (vj > v) || (vj == v && j < i);
    }
    perm[rank] = i;
    __syncthreads();

    const int src = perm[i];
    perm_ws[b * KK + i] = src;

    out[OFF_GEN   + b * KK + i] = mv[src];
    out[OFF_DISC  + b * KK + i] = disc_ll[b * KK + src];
    out[OFF_NCONS + b * KK + i] = (float)ncons[b * KK + src];
    out[OFF_NOPEN + b * KK + i] = (float)nopen[b * KK + src];
    out[OFF_APOS  + b * KK + i] = (float)actions_pos[b * KK + src];
    out[OFF_PTR   + b * KK + i] = (float)pointer[b * KK + src];

    if (i == 0) {
        int sz = size_ptr[0];
        out[OFF_WID + b] = (float)(bw < sz ? bw : sz);
    }
}

// Fused, division-free gather of all beam-indexed big arrays.
// grid = (31, B*K). blockIdx.y = bk (dst row), blockIdx.x = chunk:
//   0..11  -> hiddens  (inner 3072 float4, 12 chunks of 256)
//   12..23 -> cells
//   24..29 -> trees    (inner 1536 float4, 6 chunks of 256)
//   30     -> actions  (125 int4 -> float4)
// All data is touched exactly once (perm is a per-batch bijection) ->
// nontemporal loads/stores to keep the stream out of L2.
__global__ __launch_bounds__(256) void gather_fused(
    const f32x4* __restrict__ hiddens,
    const f32x4* __restrict__ cells,
    const f32x4* __restrict__ trees,
    const i32x4* __restrict__ actions,
    const int*   __restrict__ perm,
    float*       __restrict__ out)
{
    const int bk  = blockIdx.y;          // 0..4095
    const int c   = blockIdx.x;          // 0..30
    const int tid = threadIdx.x;         // 0..255
    const int b   = bk >> 7;             // K = 128
    const int src = perm[bk];            // wave-uniform load
    const int srow = b * KK + src;       // source row index

    if (c < 24) {
        // hiddens (c<12) or cells (c>=12): inner4 = 3072
        const bool is_h = c < 12;
        const int cc = is_h ? c : c - 12;
        const f32x4* in = is_h ? hiddens : cells;
        f32x4* o = (f32x4*)(out + (is_h ? OFF_HID : OFF_CELL));
        const int r = cc * 256 + tid;                  // 0..3071
        f32x4 v = __builtin_nontemporal_load(&in[(long)srow * 3072 + r]);
        __builtin_nontemporal_store(v, &o[(long)bk * 3072 + r]);
    } else if (c < 30) {
        // trees: inner4 = 1536
        const int r = (c - 24) * 256 + tid;            // 0..1535
        f32x4 v = __builtin_nontemporal_load(&trees[(long)srow * 1536 + r]);
        f32x4* o = (f32x4*)(out + OFF_TREE);
        __builtin_nontemporal_store(v, &o[(long)bk * 1536 + r]);
    } else {
        // actions: inner4 = 125 (int -> float)
        if (tid < 125) {
            i32x4 a = __builtin_nontemporal_load(&actions[(long)srow * 125 + tid]);
            f32x4 v;
            v.x = (float)a.x; v.y = (float)a.y; v.z = (float)a.z; v.w = (float)a.w;
            f32x4* o = (f32x4*)(out + OFF_ACT);
            __builtin_nontemporal_store(v, &o[(long)bk * 125 + tid]);
        }
    }
}

extern "C" void kernel_launch(void* const* d_in, const int* in_sizes, int n_in,
                              void* d_out, int out_size, void* d_ws, size_t ws_size,
                              hipStream_t stream) {
    const float* gen_ll      = (const float*)d_in[0];
    const float* disc_ll     = (const float*)d_in[1];
    const float* hiddens     = (const float*)d_in[2];
    const float* cells       = (const float*)d_in[3];
    const float* trees       = (const float*)d_in[4];
    const int*   beam_widths = (const int*)d_in[5];
    const int*   ncons       = (const int*)d_in[6];
    const int*   nopen       = (const int*)d_in[7];
    const int*   actions     = (const int*)d_in[8];
    const int*   actions_pos = (const int*)d_in[9];
    const int*   pointer     = (const int*)d_in[10];
    const int*   size_ptr    = (const int*)d_in[11];

    float* out = (float*)d_out;
    int*   perm_ws = (int*)d_ws;  // B*K ints

    // 1) sort + small outputs + permutation
    sort_small_kernel<<<BB, KK, 0, stream>>>(
        gen_ll, disc_ll, beam_widths, ncons, nopen, actions_pos, pointer,
        size_ptr, out, perm_ws);

    // 2) single fused gather for all big arrays
    dim3 grid(31, BB * KK);
    gather_fused<<<grid, 256, 0, stream>>>(
        (const f32x4*)hiddens, (const f32x4*)cells, (const f32x4*)trees,
        (const i32x4*)actions, perm_ws, out);
}